// Round 3
// baseline (8815.689 us; speedup 1.0000x reference)
//
#include <hip/hip_runtime.h>
#include <math.h>

#define N_STEPS 50
#define DT 0.02f

typedef float v2f __attribute__((ext_vector_type(2)));

static __device__ inline v2f v2splat(float s) { v2f r; r.x = s; r.y = s; return r; }
static __device__ inline v2f v2fma(v2f a, v2f b, v2f c) { return __builtin_elementwise_fma(a, b, c); }
static __device__ inline v2f v2relu(v2f a) { v2f z; z.x = 0.0f; z.y = 0.0f; return __builtin_elementwise_max(a, z); }

// Block = 256 threads = 4 waves, all over the SAME 64 paths (lane = path).
//   wave = (half<<1) | net :  net 0 = z-net, net 1 = q-net; half = hidden half
// Each wave computes L1 fully (64x4 FMA, duplicated across halves: 6% extra)
// then its 32-row half of L2 (+L3 partial). L3 partials exchanged via
// double-buffered LDS, ONE barrier per step. All waves redundantly integrate
// y (and Y) so no state exchange is needed. Weights are wave-uniform ->
// s_load; inner updates on float2 -> v_pk_fma_f32 where ISel supports it.
__global__ __launch_bounds__(256, 8) void bsde_kernel(
    const float* __restrict__ y0v, const float* __restrict__ Y0v,
    const float* __restrict__ qW1, const float* __restrict__ qb1,
    const float* __restrict__ qW2, const float* __restrict__ qb2,
    const float* __restrict__ qW3, const float* __restrict__ qb3,
    const float* __restrict__ zW1, const float* __restrict__ zb1,
    const float* __restrict__ zW2, const float* __restrict__ zb2,
    const float* __restrict__ zW3, const float* __restrict__ zb3,
    const float* __restrict__ dW,
    float* __restrict__ out, int B)
{
    const int lane = threadIdx.x & 63;
    const int wave = threadIdx.x >> 6;
    const int net  = wave & 1;            // 0 = z-net, 1 = q-net
    const int half = wave >> 1;           // hidden half: rows [half*32, half*32+32)
    const int p    = blockIdx.x * 64 + lane;

    // Partial L3 outputs: [buf][half][chan][lane] -- lane-stride-1, conflict-free
    __shared__ float zpart[2][2][3][64];
    __shared__ float qpart[2][2][64];

    const float* __restrict__ W1 = net ? qW1 : zW1;
    const float* __restrict__ b1 = net ? qb1 : zb1;
    const float* __restrict__ W2 = net ? qW2 : zW2;
    const float* __restrict__ b2 = net ? qb2 : zb2;
    const float* __restrict__ W3 = net ? qW3 : zW3;
    const int NOUT = net ? 1 : 3;

    const v2f* __restrict__ W1v = (const v2f*)W1;   // rows of 64 -> 32 v2f
    const v2f* __restrict__ b1v = (const v2f*)b1;
    const v2f* __restrict__ b2v = (const v2f*)b2 + half * 16;

    const float sqrt_dt = sqrtf(DT);

    float y0 = y0v[0], y1 = y0v[1], y2 = y0v[2];
    float Y  = Y0v[0];

    for (int n = 0; n < N_STEPS; ++n) {
        const float t  = (float)n * DT;
        const int   bu = n & 1;

        const v2f x0v = v2splat(t);
        const v2f x1v = v2splat(y0);
        const v2f x2v = v2splat(y1);
        const v2f x3v = v2splat(y2);

        v2f acc[16];
#pragma unroll
        for (int j = 0; j < 16; ++j) acc[j] = b2v[j];

        for (int i2 = 0; i2 < 32; ++i2) {         // i = 2*i2: two L1 rows per iter
            v2f hp = b1v[i2];
            hp = v2fma(x0v, W1v[i2],       hp);
            hp = v2fma(x1v, W1v[32 + i2],  hp);
            hp = v2fma(x2v, W1v[64 + i2],  hp);
            hp = v2fma(x3v, W1v[96 + i2],  hp);
            hp = v2relu(hp);
            const v2f* __restrict__ r0 = (const v2f*)(W2 + (2 * i2)     * 64) + half * 16;
            const v2f* __restrict__ r1 = (const v2f*)(W2 + (2 * i2 + 1) * 64) + half * 16;
            const v2f h0 = v2splat(hp.x);
            const v2f h1 = v2splat(hp.y);
#pragma unroll
            for (int j = 0; j < 16; ++j) {
                acc[j] = v2fma(h0, r0[j], acc[j]);
                acc[j] = v2fma(h1, r1[j], acc[j]);
            }
        }

        // L3 partial over this half's 32 hidden rows (bias added after halves sum)
        float o0 = 0.0f, o1 = 0.0f, o2 = 0.0f;
#pragma unroll
        for (int j = 0; j < 16; ++j) {
            const v2f hr = v2relu(acc[j]);
            const int row = half * 32 + 2 * j;
            if (NOUT == 1) {
                o0 = fmaf(hr.x, W3[row], o0);
                o0 = fmaf(hr.y, W3[row + 1], o0);
            } else {
                o0 = fmaf(hr.x, W3[row * 3 + 0], o0);
                o1 = fmaf(hr.x, W3[row * 3 + 1], o1);
                o2 = fmaf(hr.x, W3[row * 3 + 2], o2);
                o0 = fmaf(hr.y, W3[(row + 1) * 3 + 0], o0);
                o1 = fmaf(hr.y, W3[(row + 1) * 3 + 1], o1);
                o2 = fmaf(hr.y, W3[(row + 1) * 3 + 2], o2);
            }
        }

        if (net == 0) {
            zpart[bu][half][0][lane] = o0;
            zpart[bu][half][1][lane] = o1;
            zpart[bu][half][2][lane] = o2;
        } else {
            qpart[bu][half][lane] = o0;
        }
        __syncthreads();

        const float qq = qpart[bu][0][lane] + qpart[bu][1][lane] + qb3[0];
        const float z0 = zpart[bu][0][0][lane] + zpart[bu][1][0][lane] + zb3[0];
        const float z1 = zpart[bu][0][1][lane] + zpart[bu][1][1][lane] + zb3[1];
        const float z2 = zpart[bu][0][2][lane] + zpart[bu][1][2][lane] + zb3[2];
        const float f  = 0.5f * qq * qq;

        const size_t idx = ((size_t)n * (size_t)B + (size_t)p) * 3;
        const float dw0 = dW[idx + 0] * sqrt_dt;
        const float dw1 = dW[idx + 1] * sqrt_dt;
        const float dw2 = dW[idx + 2] * sqrt_dt;

        Y = Y - f * DT + (z0 * dw0 + z1 * dw1 + z2 * dw2);

        const float s0 = 0.2f + 0.1f * tanhf(y0);
        const float s1 = 0.2f + 0.1f * tanhf(y1);
        const float s2 = 0.2f + 0.1f * tanhf(y2);
        y0 = y0 + (qq - y0) * DT + s0 * dw0;
        y1 = y1 + (qq - y1) * DT + s1 * dw1;
        y2 = y2 + (qq - y2) * DT + s2 * dw2;
    }

    // Wave 0 owns the reduction (its y/Y are complete).
    if (wave == 0) {
        const float term = y0 * y0 + y1 * y1 + y2 * y2;
        const float d    = Y - term;
        float val = d * d;
#pragma unroll
        for (int off = 32; off > 0; off >>= 1)
            val += __shfl_down(val, off, 64);
        if (lane == 0)
            atomicAdd(out, val * (1.0f / (float)B));
    }
}

extern "C" void kernel_launch(void* const* d_in, const int* in_sizes, int n_in,
                              void* d_out, int out_size, void* d_ws, size_t ws_size,
                              hipStream_t stream) {
    const float* y0  = (const float*)d_in[0];
    const float* Y0  = (const float*)d_in[1];
    const float* qW1 = (const float*)d_in[2];
    const float* qb1 = (const float*)d_in[3];
    const float* qW2 = (const float*)d_in[4];
    const float* qb2 = (const float*)d_in[5];
    const float* qW3 = (const float*)d_in[6];
    const float* qb3 = (const float*)d_in[7];
    const float* zW1 = (const float*)d_in[8];
    const float* zb1 = (const float*)d_in[9];
    const float* zW2 = (const float*)d_in[10];
    const float* zb2 = (const float*)d_in[11];
    const float* zW3 = (const float*)d_in[12];
    const float* zb3 = (const float*)d_in[13];
    const float* dW  = (const float*)d_in[14];

    const int B = in_sizes[14] / (N_STEPS * 3);   // 131072
    float* out = (float*)d_out;

    hipMemsetAsync(out, 0, sizeof(float), stream);

    const int threads = 256;                       // 4 waves: 2 halves x 2 nets
    const int blocks  = B / 64;                    // 2048 blocks, same-64-path group
    bsde_kernel<<<blocks, threads, 0, stream>>>(
        y0, Y0, qW1, qb1, qW2, qb2, qW3, qb3,
        zW1, zb1, zW2, zb2, zW3, zb3, dW, out, B);
}

// Round 4
// 8602.482 us; speedup vs baseline: 1.0248x; 1.0248x over previous
//
#include <hip/hip_runtime.h>
#include <math.h>

#define N_STEPS 50
#define DT 0.02f

typedef float v2f __attribute__((ext_vector_type(2)));

static __device__ inline v2f v2splat(float s) { v2f r; r.x = s; r.y = s; return r; }
static __device__ inline v2f v2fma(v2f a, v2f b, v2f c) { return __builtin_elementwise_fma(a, b, c); }
static __device__ inline v2f v2relu(v2f a) { v2f z; z.x = 0.0f; z.y = 0.0f; return __builtin_elementwise_max(a, z); }

// Block = 256 threads = 4 waves, all over the SAME 64 paths (lane = path).
//   wave = (half<<1) | net :  net 0 = z-net, net 1 = q-net; half = hidden half
// Each wave computes L1 fully (64x4 FMA, duplicated across halves: 6% extra)
// then its 32-row half of L2 (+L3 partial). L3 partials exchanged via
// double-buffered LDS, ONE barrier per step. All waves redundantly integrate
// y (and Y) so no state exchange is needed. Weights are wave-uniform ->
// s_load; inner updates on float2 -> v_pk_fma_f32 where ISel supports it.
//
// launch_bounds(256,6): VGPR cap 85 -- natural footprint ~55-70 fits with NO
// scratch spill. (256,8) in the previous round forced 32 VGPRs and spilled
// the accumulator to memory (FETCH 2.9 GB, 6x regression).
__global__ __launch_bounds__(256, 6) void bsde_kernel(
    const float* __restrict__ y0v, const float* __restrict__ Y0v,
    const float* __restrict__ qW1, const float* __restrict__ qb1,
    const float* __restrict__ qW2, const float* __restrict__ qb2,
    const float* __restrict__ qW3, const float* __restrict__ qb3,
    const float* __restrict__ zW1, const float* __restrict__ zb1,
    const float* __restrict__ zW2, const float* __restrict__ zb2,
    const float* __restrict__ zW3, const float* __restrict__ zb3,
    const float* __restrict__ dW,
    float* __restrict__ out, int B)
{
    const int lane = threadIdx.x & 63;
    const int wave = threadIdx.x >> 6;
    const int net  = wave & 1;            // 0 = z-net, 1 = q-net
    const int half = wave >> 1;           // hidden half: rows [half*32, half*32+32)
    const int p    = blockIdx.x * 64 + lane;

    // Partial L3 outputs: [buf][half][chan][lane] -- lane-stride-1, conflict-free
    __shared__ float zpart[2][2][3][64];
    __shared__ float qpart[2][2][64];

    const float* __restrict__ W1 = net ? qW1 : zW1;
    const float* __restrict__ b1 = net ? qb1 : zb1;
    const float* __restrict__ W2 = net ? qW2 : zW2;
    const float* __restrict__ b2 = net ? qb2 : zb2;
    const float* __restrict__ W3 = net ? qW3 : zW3;
    const int NOUT = net ? 1 : 3;

    const v2f* __restrict__ W1v = (const v2f*)W1;   // rows of 64 -> 32 v2f
    const v2f* __restrict__ b1v = (const v2f*)b1;
    const v2f* __restrict__ b2v = (const v2f*)b2 + half * 16;

    const float sqrt_dt = sqrtf(DT);

    float y0 = y0v[0], y1 = y0v[1], y2 = y0v[2];
    float Y  = Y0v[0];

    for (int n = 0; n < N_STEPS; ++n) {
        const float t  = (float)n * DT;
        const int   bu = n & 1;

        const v2f x0v = v2splat(t);
        const v2f x1v = v2splat(y0);
        const v2f x2v = v2splat(y1);
        const v2f x3v = v2splat(y2);

        v2f acc[16];
#pragma unroll
        for (int j = 0; j < 16; ++j) acc[j] = b2v[j];

        for (int i2 = 0; i2 < 32; ++i2) {         // i = 2*i2: two L1 rows per iter
            v2f hp = b1v[i2];
            hp = v2fma(x0v, W1v[i2],       hp);
            hp = v2fma(x1v, W1v[32 + i2],  hp);
            hp = v2fma(x2v, W1v[64 + i2],  hp);
            hp = v2fma(x3v, W1v[96 + i2],  hp);
            hp = v2relu(hp);
            const v2f* __restrict__ r0 = (const v2f*)(W2 + (2 * i2)     * 64) + half * 16;
            const v2f* __restrict__ r1 = (const v2f*)(W2 + (2 * i2 + 1) * 64) + half * 16;
            const v2f h0 = v2splat(hp.x);
            const v2f h1 = v2splat(hp.y);
#pragma unroll
            for (int j = 0; j < 16; ++j) {
                acc[j] = v2fma(h0, r0[j], acc[j]);
                acc[j] = v2fma(h1, r1[j], acc[j]);
            }
        }

        // L3 partial over this half's 32 hidden rows (bias added after halves sum)
        float o0 = 0.0f, o1 = 0.0f, o2 = 0.0f;
#pragma unroll
        for (int j = 0; j < 16; ++j) {
            const v2f hr = v2relu(acc[j]);
            const int row = half * 32 + 2 * j;
            if (NOUT == 1) {
                o0 = fmaf(hr.x, W3[row], o0);
                o0 = fmaf(hr.y, W3[row + 1], o0);
            } else {
                o0 = fmaf(hr.x, W3[row * 3 + 0], o0);
                o1 = fmaf(hr.x, W3[row * 3 + 1], o1);
                o2 = fmaf(hr.x, W3[row * 3 + 2], o2);
                o0 = fmaf(hr.y, W3[(row + 1) * 3 + 0], o0);
                o1 = fmaf(hr.y, W3[(row + 1) * 3 + 1], o1);
                o2 = fmaf(hr.y, W3[(row + 1) * 3 + 2], o2);
            }
        }

        if (net == 0) {
            zpart[bu][half][0][lane] = o0;
            zpart[bu][half][1][lane] = o1;
            zpart[bu][half][2][lane] = o2;
        } else {
            qpart[bu][half][lane] = o0;
        }
        __syncthreads();

        const float qq = qpart[bu][0][lane] + qpart[bu][1][lane] + qb3[0];
        const float z0 = zpart[bu][0][0][lane] + zpart[bu][1][0][lane] + zb3[0];
        const float z1 = zpart[bu][0][1][lane] + zpart[bu][1][1][lane] + zb3[1];
        const float z2 = zpart[bu][0][2][lane] + zpart[bu][1][2][lane] + zb3[2];
        const float f  = 0.5f * qq * qq;

        const size_t idx = ((size_t)n * (size_t)B + (size_t)p) * 3;
        const float dw0 = dW[idx + 0] * sqrt_dt;
        const float dw1 = dW[idx + 1] * sqrt_dt;
        const float dw2 = dW[idx + 2] * sqrt_dt;

        Y = Y - f * DT + (z0 * dw0 + z1 * dw1 + z2 * dw2);

        const float s0 = 0.2f + 0.1f * tanhf(y0);
        const float s1 = 0.2f + 0.1f * tanhf(y1);
        const float s2 = 0.2f + 0.1f * tanhf(y2);
        y0 = y0 + (qq - y0) * DT + s0 * dw0;
        y1 = y1 + (qq - y1) * DT + s1 * dw1;
        y2 = y2 + (qq - y2) * DT + s2 * dw2;
    }

    // Wave 0 owns the reduction (its y/Y are complete).
    if (wave == 0) {
        const float term = y0 * y0 + y1 * y1 + y2 * y2;
        const float d    = Y - term;
        float val = d * d;
#pragma unroll
        for (int off = 32; off > 0; off >>= 1)
            val += __shfl_down(val, off, 64);
        if (lane == 0)
            atomicAdd(out, val * (1.0f / (float)B));
    }
}

extern "C" void kernel_launch(void* const* d_in, const int* in_sizes, int n_in,
                              void* d_out, int out_size, void* d_ws, size_t ws_size,
                              hipStream_t stream) {
    const float* y0  = (const float*)d_in[0];
    const float* Y0  = (const float*)d_in[1];
    const float* qW1 = (const float*)d_in[2];
    const float* qb1 = (const float*)d_in[3];
    const float* qW2 = (const float*)d_in[4];
    const float* qb2 = (const float*)d_in[5];
    const float* qW3 = (const float*)d_in[6];
    const float* qb3 = (const float*)d_in[7];
    const float* zW1 = (const float*)d_in[8];
    const float* zb1 = (const float*)d_in[9];
    const float* zW2 = (const float*)d_in[10];
    const float* zb2 = (const float*)d_in[11];
    const float* zW3 = (const float*)d_in[12];
    const float* zb3 = (const float*)d_in[13];
    const float* dW  = (const float*)d_in[14];

    const int B = in_sizes[14] / (N_STEPS * 3);   // 131072
    float* out = (float*)d_out;

    hipMemsetAsync(out, 0, sizeof(float), stream);

    const int threads = 256;                       // 4 waves: 2 halves x 2 nets
    const int blocks  = B / 64;                    // 2048 blocks, same-64-path group
    bsde_kernel<<<blocks, threads, 0, stream>>>(
        y0, Y0, qW1, qb1, qW2, qb2, qW3, qb3,
        zW1, zb1, zW2, zb2, zW3, zb3, dW, out, B);
}

// Round 5
// 1503.672 us; speedup vs baseline: 5.8628x; 5.7210x over previous
//
#include <hip/hip_runtime.h>
#include <math.h>

#define N_STEPS 50
#define DT 0.02f

// One wave computes ONE net (z or q) over ONE hidden-half (rows [H0,H0+32)).
// NOUT and H0 are template constants and the weight pointers arrive directly
// from kernel args at each call site, so every weight address is
// SGPR + compile-time offset -> s_load (zero VALU/VMEM cost). No
// thread-varying pointer selects anywhere (that was the round-3/4 disaster:
// `net ? qW1 : zW1` put weight bases in VGPRs -> vector loads + scratch).
template <int NOUT, int H0>
__device__ inline void mlp_half(const float* __restrict__ W1, const float* __restrict__ b1,
                                const float* __restrict__ W2, const float* __restrict__ b2,
                                const float* __restrict__ W3,
                                float x0, float x1, float x2, float x3,
                                float* __restrict__ outv)
{
    float acc[32];
#pragma unroll
    for (int j = 0; j < 32; ++j) acc[j] = b2[H0 + j];

    for (int i = 0; i < 64; ++i) {            // rolled: uniform s_load stream
        float h = b1[i];
        h = fmaf(x0, W1[i],        h);
        h = fmaf(x1, W1[64 + i],   h);
        h = fmaf(x2, W1[128 + i],  h);
        h = fmaf(x3, W1[192 + i],  h);
        h = fmaxf(h, 0.0f);
        const float* __restrict__ w2row = W2 + i * 64 + H0;
#pragma unroll
        for (int j = 0; j < 32; ++j) acc[j] = fmaf(h, w2row[j], acc[j]);
    }

#pragma unroll
    for (int c = 0; c < NOUT; ++c) outv[c] = 0.0f;   // bias added after halves sum
#pragma unroll
    for (int j = 0; j < 32; ++j) {
        const float hr = fmaxf(acc[j], 0.0f);
#pragma unroll
        for (int c = 0; c < NOUT; ++c)
            outv[c] = fmaf(hr, W3[(H0 + j) * NOUT + c], outv[c]);
    }
}

// Block = 256 threads = 4 waves over the SAME 64 paths (lane = path):
//   wave 0: z-net rows [0,32)   wave 1: z-net rows [32,64)
//   wave 2: q-net rows [0,32)   wave 3: q-net rows [32,64)
// Partials exchanged via double-buffered LDS, ONE barrier per step. All waves
// redundantly integrate y,Y (bitwise-identical f32) so no state exchange.
__global__ void bsde_kernel(
    const float* __restrict__ y0v, const float* __restrict__ Y0v,
    const float* __restrict__ qW1, const float* __restrict__ qb1,
    const float* __restrict__ qW2, const float* __restrict__ qb2,
    const float* __restrict__ qW3, const float* __restrict__ qb3,
    const float* __restrict__ zW1, const float* __restrict__ zb1,
    const float* __restrict__ zW2, const float* __restrict__ zb2,
    const float* __restrict__ zW3, const float* __restrict__ zb3,
    const float* __restrict__ dW,
    float* __restrict__ out, int B)
{
    const int lane = threadIdx.x & 63;
    const int wave = threadIdx.x >> 6;
    const int p    = blockIdx.x * 64 + lane;

    // [buf][half][chan][lane] -- lane-stride-1, conflict-free
    __shared__ float zpart[2][2][3][64];
    __shared__ float qpart[2][2][64];

    const float sqrt_dt = sqrtf(DT);

    float y0 = y0v[0], y1 = y0v[1], y2 = y0v[2];
    float Y  = Y0v[0];

    for (int n = 0; n < N_STEPS; ++n) {
        const float t  = (float)n * DT;
        const int   bu = n & 1;

        // dW load issued before the MLP so vmcnt retires under compute
        const size_t idx = ((size_t)n * (size_t)B + (size_t)p) * 3;
        const float dw0 = dW[idx + 0] * sqrt_dt;
        const float dw1 = dW[idx + 1] * sqrt_dt;
        const float dw2 = dW[idx + 2] * sqrt_dt;

        if (wave == 0) {
            float o[3];
            mlp_half<3, 0>(zW1, zb1, zW2, zb2, zW3, t, y0, y1, y2, o);
            zpart[bu][0][0][lane] = o[0];
            zpart[bu][0][1][lane] = o[1];
            zpart[bu][0][2][lane] = o[2];
        } else if (wave == 1) {
            float o[3];
            mlp_half<3, 32>(zW1, zb1, zW2, zb2, zW3, t, y0, y1, y2, o);
            zpart[bu][1][0][lane] = o[0];
            zpart[bu][1][1][lane] = o[1];
            zpart[bu][1][2][lane] = o[2];
        } else if (wave == 2) {
            float o[1];
            mlp_half<1, 0>(qW1, qb1, qW2, qb2, qW3, t, y0, y1, y2, o);
            qpart[bu][0][lane] = o[0];
        } else {
            float o[1];
            mlp_half<1, 32>(qW1, qb1, qW2, qb2, qW3, t, y0, y1, y2, o);
            qpart[bu][1][lane] = o[0];
        }
        __syncthreads();

        const float qq = qpart[bu][0][lane] + qpart[bu][1][lane] + qb3[0];
        const float z0 = zpart[bu][0][0][lane] + zpart[bu][1][0][lane] + zb3[0];
        const float z1 = zpart[bu][0][1][lane] + zpart[bu][1][1][lane] + zb3[1];
        const float z2 = zpart[bu][0][2][lane] + zpart[bu][1][2][lane] + zb3[2];
        const float f  = 0.5f * qq * qq;

        Y = Y - f * DT + (z0 * dw0 + z1 * dw1 + z2 * dw2);

        const float s0 = 0.2f + 0.1f * tanhf(y0);
        const float s1 = 0.2f + 0.1f * tanhf(y1);
        const float s2 = 0.2f + 0.1f * tanhf(y2);
        y0 = y0 + (qq - y0) * DT + s0 * dw0;
        y1 = y1 + (qq - y1) * DT + s1 * dw1;
        y2 = y2 + (qq - y2) * DT + s2 * dw2;
    }

    // Wave 0 owns the reduction (its y/Y are complete).
    if (wave == 0) {
        const float term = y0 * y0 + y1 * y1 + y2 * y2;
        const float d    = Y - term;
        float val = d * d;
#pragma unroll
        for (int off = 32; off > 0; off >>= 1)
            val += __shfl_down(val, off, 64);
        if (lane == 0)
            atomicAdd(out, val * (1.0f / (float)B));
    }
}

extern "C" void kernel_launch(void* const* d_in, const int* in_sizes, int n_in,
                              void* d_out, int out_size, void* d_ws, size_t ws_size,
                              hipStream_t stream) {
    const float* y0  = (const float*)d_in[0];
    const float* Y0  = (const float*)d_in[1];
    const float* qW1 = (const float*)d_in[2];
    const float* qb1 = (const float*)d_in[3];
    const float* qW2 = (const float*)d_in[4];
    const float* qb2 = (const float*)d_in[5];
    const float* qW3 = (const float*)d_in[6];
    const float* qb3 = (const float*)d_in[7];
    const float* zW1 = (const float*)d_in[8];
    const float* zb1 = (const float*)d_in[9];
    const float* zW2 = (const float*)d_in[10];
    const float* zb2 = (const float*)d_in[11];
    const float* zW3 = (const float*)d_in[12];
    const float* zb3 = (const float*)d_in[13];
    const float* dW  = (const float*)d_in[14];

    const int B = in_sizes[14] / (N_STEPS * 3);   // 131072
    float* out = (float*)d_out;

    hipMemsetAsync(out, 0, sizeof(float), stream);

    const int threads = 256;                       // 4 waves: 2 halves x 2 nets
    const int blocks  = B / 64;                    // 2048 blocks
    bsde_kernel<<<blocks, threads, 0, stream>>>(
        y0, Y0, qW1, qb1, qW2, qb2, qW3, qb3,
        zW1, zb1, zW2, zb2, zW3, zb3, dW, out, B);
}